// Round 16
// baseline (807.287 us; speedup 1.0000x reference)
//
#include <hip/hip_runtime.h>
#include <hip/hip_bf16.h>

// x[N,128] f32, edge_index[2,E] int, edge_label[E,4] f32,
// weight[512,256] f32, trans_weight[4,128] f32, bias[256] f32 -> out[N,256] f32
//
// Pipeline:
//   memset     : bucket counters + per-bucket completion flags
//   cvt_bin    : role-split grid (bin | x->bf16 cvt | wb fragment pack)
//   sort_accum : block per (bucket,dir); LDS CSR sort + u64 label sums + 16-lane
//                dwordx4 gathers (4-deep), bf16 means -> global. If FUSE: the
//                second finisher of each bucket (threadfence + device atomicAdd
//                on flags) computes the bucket's 2x 64x256 MFMA output tiles
//                from the L2-hot means (gemm dispatch eliminated, overlapped).
//   gemm_mfma  : only launched when ws too small for staging (fallback = r13).

#define BK 128
#define BKSH 7        // log2(BK)
#define CHUNK 4096
#define CAPSEG 4096   // fixed entries per bucket segment (mean 2046, sigma ~45)
#define CSSH 12       // log2(CAPSEG)
#define NB_CVT 256

typedef unsigned short u16;
typedef unsigned long long u64;
typedef __attribute__((ext_vector_type(4))) float f32x4;
typedef __attribute__((ext_vector_type(8))) short bf16x8;

__device__ inline unsigned pk_bf16(float a, float b) {
    __hip_bfloat162 h;
    h.x = __float2bfloat16(a);
    h.y = __float2bfloat16(b);
    return *reinterpret_cast<unsigned*>(&h);
}
__device__ inline float2 upk_bf16(unsigned u) {
    __hip_bfloat162 h = *reinterpret_cast<__hip_bfloat162*>(&u);
    return make_float2(__bfloat162float(h.x), __bfloat162float(h.y));
}
__device__ inline u16 f2bf(float f) {
    __hip_bfloat16 h = __float2bfloat16(f);
    return *reinterpret_cast<u16*>(&h);
}

// Fused independent pre-phases: bin + cvt + wb-pack (no cross-role data deps).
__global__ __launch_bounds__(256) void cvt_bin(
    const float2* __restrict__ x2, unsigned* __restrict__ xh,
    const int* __restrict__ eidx, const float4* __restrict__ elab4,
    int* __restrict__ cnt_r, int* __restrict__ cnt_c,
    uint2* __restrict__ ent_r, uint2* __restrict__ ent_c,
    const float* __restrict__ w, const float* __restrict__ tw,
    u16* __restrict__ wb, int n2, int E, int nbk, int nchunk)
{
    __shared__ int smem[2048];   // 8KB union: bin cB[nbk<=2048] / wb P[8][256]
    const int t = threadIdx.x;
    const unsigned bid = blockIdx.x;

    if (bid < 2u * nchunk) {
        // ---------------- bin role ----------------
        int* cB = smem;
        const int dir = (bid >= (unsigned)nchunk);
        const int base = (dir ? bid - nchunk : bid) * CHUNK;
        const int* __restrict__ osrc = eidx + (dir ? (size_t)E : 0);   // own id
        const int* __restrict__ psrc = eidx + (dir ? 0 : (size_t)E);   // partner id
        int* __restrict__ cnt = dir ? cnt_c : cnt_r;
        uint2* __restrict__ ent = dir ? ent_c : ent_r;

        for (int i = t; i < nbk; i += 256) cB[i] = 0;
        __syncthreads();

        int4 own4[4], par4[4];
        unsigned lq[16];
        bool ok[4];
        #pragma unroll
        for (int jj = 0; jj < 4; ++jj) {
            const int e0 = base + (jj * 256 + t) * 4;
            ok[jj] = (e0 < E);             // E % 4 == 0; chunk-aligned
            if (ok[jj]) {
                own4[jj] = *(const int4*)(osrc + e0);
                par4[jj] = *(const int4*)(psrc + e0);
                #pragma unroll
                for (int k = 0; k < 4; ++k) {
                    const float4 lb = elab4[e0 + k];
                    const unsigned q0 = (unsigned)(lb.x * 255.f + 0.5f);
                    const unsigned q1 = (unsigned)(lb.y * 255.f + 0.5f);
                    const unsigned q2 = (unsigned)(lb.z * 255.f + 0.5f);
                    const unsigned q3 = (unsigned)(lb.w * 255.f + 0.5f);
                    lq[jj * 4 + k] = q0 | (q1 << 8) | (q2 << 16) | (q3 << 24);
                }
                atomicAdd(&cB[((unsigned)own4[jj].x) >> BKSH], 1);
                atomicAdd(&cB[((unsigned)own4[jj].y) >> BKSH], 1);
                atomicAdd(&cB[((unsigned)own4[jj].z) >> BKSH], 1);
                atomicAdd(&cB[((unsigned)own4[jj].w) >> BKSH], 1);
            }
        }
        __syncthreads();
        for (int b = t; b < nbk; b += 256) {
            const int c = cB[b];
            cB[b] = c ? ((b << CSSH) + atomicAdd(&cnt[b], c)) : 0;
        }
        __syncthreads();
        #pragma unroll
        for (int jj = 0; jj < 4; ++jj) {
            if (ok[jj]) {
                const int owns[4] = {own4[jj].x, own4[jj].y, own4[jj].z, own4[jj].w};
                const int pars[4] = {par4[jj].x, par4[jj].y, par4[jj].z, par4[jj].w};
                #pragma unroll
                for (int k = 0; k < 4; ++k) {
                    const unsigned own = (unsigned)owns[k];
                    const int p = atomicAdd(&cB[own >> BKSH], 1);
                    ent[p] = make_uint2((unsigned)pars[k] | ((own & (BK - 1u)) << 17),
                                        lq[jj * 4 + k]);
                }
            }
        }
        return;
    }

    if (bid < 2u * nchunk + NB_CVT) {
        // ---------------- cvt role ----------------
        const int cb = bid - 2 * nchunk;
        const int gsz = NB_CVT * 256;
        for (int i = cb * 256 + t; i < n2; i += gsz) {
            const float2 v = x2[i];
            xh[i] = pk_bf16(v.x, v.y);
        }
        return;
    }

    // ---------------- wb-pack role ----------------
    // wb[((ks*16+ct)*64+lane)*8+j] = B_eff[ks*32+(lane>>4)*8+j][ct*16+(lane&15)]
    // B_eff rows: [0:128)=W[0:128], [128:256)=W[256:384], [256:260)=P1,
    // [260:264)=P3, zero pad to 288.
    float (*P)[256] = (float(*)[256])smem;
    const int pid0 = (bid - 2 * nchunk - NB_CVT) * 256;
    if (pid0 + 255 >= 8192) {              // packs some k>=256 -> needs P1/P3
        for (int q = t; q < 2048; q += 256) {
            const int l = q >> 8;
            const int cidx = q & 255;
            const int lr = l & 3;
            const int off = (l < 4) ? 128 : 384;
            float s = 0.f;
            for (int c = 0; c < 128; ++c)
                s = fmaf(tw[lr * 128 + c], w[(size_t)(off + c) * 256 + cidx], s);
            P[l][cidx] = s;
        }
        __syncthreads();
    }
    const int pid = pid0 + t;
    if (pid >= 9 * 16 * 64) return;
    const int ks = pid >> 10;
    const int ct = (pid >> 6) & 15;
    const int l  = pid & 63;
    const int col = ct * 16 + (l & 15);
    const int k0 = ks * 32 + ((l >> 4) << 3);
    u16 v[8];
    #pragma unroll
    for (int j = 0; j < 8; ++j) {
        const int k = k0 + j;
        float f = 0.f;
        if (k < 128)      f = w[(size_t)k * 256 + col];
        else if (k < 256) f = w[(size_t)(k + 128) * 256 + col];
        else if (k < 264) f = P[k - 256][col];
        v[j] = f2bf(f);
    }
    *(uint4*)(wb + (size_t)pid * 8) = *(uint4*)v;
}

__device__ inline void addrow(float* acc, const uint4 r) {
    const float2 a = upk_bf16(r.x), b = upk_bf16(r.y),
                 c = upk_bf16(r.z), d = upk_bf16(r.w);
    acc[0] += a.x; acc[1] += a.y; acc[2] += b.x; acc[3] += b.y;
    acc[4] += c.x; acc[5] += c.y; acc[6] += d.x; acc[7] += d.y;
}

// 64x256 output tile at node0, A read directly from global means (r13-proven).
__device__ inline void gemm_tile(
    int node0, const u16* __restrict__ om_h, const u16* __restrict__ im_h,
    const u16* __restrict__ lab_h, const u16* __restrict__ wb,
    const float* __restrict__ bias, float* __restrict__ out, int nn,
    int wid, int lane)
{
    const int m15 = lane & 15;
    const int kq  = lane >> 4;
    f32x4 acc[4][4];
    #pragma unroll
    for (int i = 0; i < 4; ++i)
        #pragma unroll
        for (int j = 0; j < 4; ++j)
            acc[i][j] = (f32x4){0.f, 0.f, 0.f, 0.f};

    for (int ks = 0; ks < 9; ++ks) {
        const int k0 = ks * 32 + kq * 8;
        bf16x8 af[4], bfr[4];
        #pragma unroll
        for (int nt = 0; nt < 4; ++nt) {
            const int gn = node0 + nt * 16 + m15;
            bf16x8 a = (bf16x8){0, 0, 0, 0, 0, 0, 0, 0};
            if (gn < nn && k0 < 264) {
                const u16* p = (k0 < 128) ? om_h + (size_t)gn * 128 + k0
                             : (k0 < 256) ? im_h + (size_t)gn * 128 + (k0 - 128)
                                          : lab_h + (size_t)gn * 8;
                a = *(const bf16x8*)p;
            }
            af[nt] = a;
        }
        #pragma unroll
        for (int c2 = 0; c2 < 4; ++c2)
            bfr[c2] = *(const bf16x8*)(wb + ((size_t)((ks * 16 + wid * 4 + c2) * 64 + lane)) * 8);
        #pragma unroll
        for (int nt = 0; nt < 4; ++nt)
            #pragma unroll
            for (int c2 = 0; c2 < 4; ++c2)
                acc[nt][c2] = __builtin_amdgcn_mfma_f32_16x16x32_bf16(
                    af[nt], bfr[c2], acc[nt][c2], 0, 0, 0);
    }

    #pragma unroll
    for (int nt = 0; nt < 4; ++nt) {
        const int gnb = node0 + nt * 16 + kq * 4;
        #pragma unroll
        for (int c2 = 0; c2 < 4; ++c2) {
            const int oc = wid * 64 + c2 * 16 + m15;
            const float bv = bias[oc];
            #pragma unroll
            for (int r = 0; r < 4; ++r) {
                const int gn = gnb + r;
                if (gn < nn)
                    __builtin_nontemporal_store(acc[nt][c2][r] + bv,
                                                &out[(size_t)gn * 256 + oc]);
            }
        }
    }
}

// Fused CSR sort (in LDS) + accumulate; optional last-finisher GEMM tail.
__global__ __launch_bounds__(256) void sort_accum(
    const uint2* __restrict__ ent1_r, const uint2* __restrict__ ent1_c,
    const int* __restrict__ cnt_r, const int* __restrict__ cnt_c,
    const uint4* __restrict__ xh4,
    uint4* __restrict__ om4, uint4* __restrict__ im4,
    u16* __restrict__ lab_h, int* __restrict__ flags,
    const u16* __restrict__ wb, const float* __restrict__ bias,
    float* __restrict__ out, int nn, int nbk, int fuse)
{
    __shared__ unsigned sorted[CAPSEG];
    __shared__ int hist[BK], sc[BK], curs[BK];
    __shared__ u64 labacc[BK];
    __shared__ int sflag;
    const int t = threadIdx.x;
    const int dir = (blockIdx.x >= (unsigned)nbk);
    const int b = blockIdx.x - (dir ? nbk : 0);
    const uint2* __restrict__ buf1 = (dir ? ent1_c : ent1_r) + ((size_t)b << CSSH);
    uint4* __restrict__ mean4 = dir ? im4 : om4;
    int cnt = (dir ? cnt_c : cnt_r)[b];
    if (cnt > CAPSEG) cnt = CAPSEG;        // statistically impossible; safety clamp

    if (t < BK) { hist[t] = 0; labacc[t] = 0ull; }
    __syncthreads();
    for (int i = t; i < cnt; i += 256) {
        const uint2 en = buf1[i];
        const unsigned local = en.x >> 17;
        atomicAdd(&hist[local], 1);
        const unsigned lv = en.y;
        const u64 spread = (u64)(lv & 255u) | ((u64)((lv >> 8) & 255u) << 16)
                         | ((u64)((lv >> 16) & 255u) << 32) | ((u64)(lv >> 24) << 48);
        atomicAdd(&labacc[local], spread);
    }
    __syncthreads();
    if (t < BK) sc[t] = hist[t];
    __syncthreads();
    for (int s = 1; s < BK; s <<= 1) {
        int v = 0;
        if (t < BK && t >= s) v = sc[t - s];
        __syncthreads();
        if (t < BK) sc[t] += v;
        __syncthreads();
    }
    if (t < BK) {
        curs[t] = sc[t] - hist[t];
        const int gn = b * BK + t;
        if (gn < nn) {
            const u64 sv = labacc[t];
            const float inv = (1.f / 255.f) / fmaxf((float)hist[t], 1.f);
            u16 lm[4];
            #pragma unroll
            for (int l = 0; l < 4; ++l)
                lm[l] = f2bf((float)((sv >> (16 * l)) & 0xFFFFu) * inv);
            *(uint2*)(lab_h + (size_t)gn * 8 + dir * 4) = *(uint2*)lm;
        }
    }
    __syncthreads();
    for (int i = t; i < cnt; i += 256) {
        const uint2 en = buf1[i];
        const int p = atomicAdd(&curs[en.x >> 17], 1);
        sorted[p] = en.x & 0x1FFFFu;       // partner only
    }
    __syncthreads();

    // accumulate: wave per node; 4-deep gather pipeline (16 entries/iter)
    const int wid = t >> 6;
    const int lane = t & 63;
    const int g = lane >> 4;               // edge group 0..3
    const int sl = lane & 15;              // 16B sub-row
    for (int local = wid; local < BK; local += 4) {
        const int gn = b * BK + local;
        if (gn >= nn) continue;            // wave-uniform branch
        const int segC = hist[local];
        const int segS = sc[local] - segC;
        float acc[8] = {0.f, 0.f, 0.f, 0.f, 0.f, 0.f, 0.f, 0.f};
        for (int i = 0; i < segC; i += 16) {
            const int rem = segC - i;
            const bool h0 = (g < rem);
            const bool h1 = (g + 4 < rem);
            const bool h2 = (g + 8 < rem);
            const bool h3 = (g + 12 < rem);
            const unsigned p0 = h0 ? sorted[segS + i + g] : 0u;
            const unsigned p1 = h1 ? sorted[segS + i + 4 + g] : 0u;
            const unsigned p2 = h2 ? sorted[segS + i + 8 + g] : 0u;
            const unsigned p3 = h3 ? sorted[segS + i + 12 + g] : 0u;
            uint4 r0, r1, r2, r3;
            if (h0) r0 = xh4[(size_t)p0 * 16 + sl];
            if (h1) r1 = xh4[(size_t)p1 * 16 + sl];
            if (h2) r2 = xh4[(size_t)p2 * 16 + sl];
            if (h3) r3 = xh4[(size_t)p3 * 16 + sl];
            if (h0) addrow(acc, r0);
            if (h1) addrow(acc, r1);
            if (h2) addrow(acc, r2);
            if (h3) addrow(acc, r3);
        }
        #pragma unroll
        for (int j = 0; j < 8; ++j) {
            acc[j] += __shfl_xor(acc[j], 16);
            acc[j] += __shfl_xor(acc[j], 32);
        }
        if (g == 0) {
            const float inv = 1.0f / fmaxf((float)segC, 1.0f);
            uint4 o;
            o.x = pk_bf16(acc[0] * inv, acc[1] * inv);
            o.y = pk_bf16(acc[2] * inv, acc[3] * inv);
            o.z = pk_bf16(acc[4] * inv, acc[5] * inv);
            o.w = pk_bf16(acc[6] * inv, acc[7] * inv);
            mean4[(size_t)gn * 16 + sl] = o;
        }
    }

    if (!fuse) return;

    // ---- last-finisher GEMM tail: second block of this bucket does the tile ----
    __syncthreads();                       // drains all waves' mean stores to L2
    if (t == 0) {
        __threadfence();                   // device-scope release of our means
        sflag = atomicAdd(&flags[b], 1);
    }
    __syncthreads();
    if (sflag == 1) {
        __threadfence();                   // acquire: sibling's means visible
        gemm_tile(b * BK,      (const u16*)om4, (const u16*)im4, lab_h, wb,
                  bias, out, nn, wid, lane);
        gemm_tile(b * BK + 64, (const u16*)om4, (const u16*)im4, lab_h, wb,
                  bias, out, nn, wid, lane);
    }
}

// Fallback standalone GEMM (r13-proven), used when ws can't hold staging.
__global__ __launch_bounds__(256) void gemm_mfma(
    const u16* __restrict__ om_h, const u16* __restrict__ im_h,
    const u16* __restrict__ lab_h, const u16* __restrict__ wb,
    const float* __restrict__ bias, float* __restrict__ out, int nn)
{
    gemm_tile(blockIdx.x * 64, om_h, im_h, lab_h, wb, bias, out, nn,
              threadIdx.x >> 6, threadIdx.x & 63);
}

extern "C" void kernel_launch(void* const* d_in, const int* in_sizes, int n_in,
                              void* d_out, int out_size, void* d_ws, size_t ws_size,
                              hipStream_t stream) {
    const float* x      = (const float*)d_in[0];
    const int*   eidx   = (const int*)d_in[1];
    const float* elabel = (const float*)d_in[2];
    const float* weight = (const float*)d_in[3];
    const float* tw     = (const float*)d_in[4];
    const float* bias   = (const float*)d_in[5];

    const int n = in_sizes[0] / 128;       // n_nodes (100000 < 2^17)
    const int E = in_sizes[2] / 4;         // n_edges (1.6M, multiple of 4)
    const int nbk = (n + BK - 1) / BK;     // buckets (782)
    const int nchunk = (E + CHUNK - 1) / CHUNK;

    // ---- common ws allocations ----
    char* wsb = (char*)d_ws;
    u16* om_h  = (u16*)wsb;  wsb += (size_t)n * 256;
    u16* im_h  = (u16*)wsb;  wsb += (size_t)n * 256;
    u16* lab_h = (u16*)wsb;  wsb += (size_t)n * 16;
    u16* wb    = (u16*)wsb;  wsb += 9216 * 16;
    int* cnt_r = (int*)wsb;  wsb += nbk * 4;     // memset region: cnt_r,cnt_c,flags
    int* cnt_c = (int*)wsb;  wsb += nbk * 4;
    int* flags = (int*)wsb;  wsb += nbk * 4;

    // ---- staging: prefer d_ws (enables fused gemm tail); else d_out (r13) ----
    const size_t staging_bytes = (size_t)n * 256 + 2 * (((size_t)nbk << CSSH) * 8);
    const size_t used = (size_t)(wsb - (char*)d_ws);
    const int fuse = (used + staging_bytes <= ws_size) ? 1 : 0;
    char* stg = fuse ? wsb : (char*)d_out;
    unsigned* xh  = (unsigned*)stg;
    uint2* ent1_r = (uint2*)(stg + (size_t)n * 256);
    uint2* ent1_c = ent1_r + ((size_t)nbk << CSSH);

    hipMemsetAsync(cnt_r, 0, (size_t)3 * nbk * sizeof(int), stream);

    hipLaunchKernelGGL(cvt_bin, dim3(2 * nchunk + NB_CVT + 36), dim3(256), 0, stream,
                       (const float2*)x, xh, eidx, (const float4*)elabel,
                       cnt_r, cnt_c, ent1_r, ent1_c,
                       weight, tw, wb, n * 64, E, nbk, nchunk);

    hipLaunchKernelGGL(sort_accum, dim3(2 * nbk), dim3(256), 0, stream,
                       ent1_r, ent1_c, cnt_r, cnt_c, (const uint4*)xh,
                       (uint4*)om_h, (uint4*)im_h, lab_h, flags,
                       wb, bias, (float*)d_out, n, nbk, fuse);

    if (!fuse)
        hipLaunchKernelGGL(gemm_mfma, dim3((n + 63) / 64), dim3(256), 0, stream,
                           om_h, im_h, lab_h, wb, bias, (float*)d_out, n);
}

// Round 17
// 261.852 us; speedup vs baseline: 3.0830x; 3.0830x over previous
//
#include <hip/hip_runtime.h>
#include <hip/hip_bf16.h>

// x[N,128] f32, edge_index[2,E] int, edge_label[E,4] f32,
// weight[512,256] f32, trans_weight[4,128] f32, bias[256] f32 -> out[N,256] f32
//
// Pipeline (4 dispatches) — round-13 configuration (best measured: 262 µs):
//   memset     : per-bucket entry counters (2*nbk ints)
//   cvt_bin    : role-split grid (bin | x->bf16 cvt | wb fragment pack)
//   sort_accum : block per (bucket,dir); LDS CSR sort + u64 label sums, then
//                wave-per-node 16-lane dwordx4 gathers (4-deep pipeline),
//                shfl reduce, bf16 means + interleaved label means (lab_h)
//   gemm_mfma  : 64x256 tile, 4 waves, A-fragments loaded DIRECTLY from global
//                (no LDS, no barrier), mfma_f32_16x16x32_bf16, K=288,
//                nontemporal output stores

#define BK 128
#define CHUNK 4096
#define CAPSEG 4096   // fixed entries per bucket segment (mean 2046, sigma ~45)
#define NB_CVT 256

typedef unsigned short u16;
typedef unsigned long long u64;
typedef __attribute__((ext_vector_type(4))) float f32x4;
typedef __attribute__((ext_vector_type(8))) short bf16x8;

__device__ inline unsigned pk_bf16(float a, float b) {
    __hip_bfloat162 h;
    h.x = __float2bfloat16(a);
    h.y = __float2bfloat16(b);
    return *reinterpret_cast<unsigned*>(&h);
}
__device__ inline float2 upk_bf16(unsigned u) {
    __hip_bfloat162 h = *reinterpret_cast<__hip_bfloat162*>(&u);
    return make_float2(__bfloat162float(h.x), __bfloat162float(h.y));
}
__device__ inline u16 f2bf(float f) {
    __hip_bfloat16 h = __float2bfloat16(f);
    return *reinterpret_cast<u16*>(&h);
}

// Fused independent pre-phases: bin + cvt + wb-pack (no cross-role data deps).
__global__ __launch_bounds__(256) void cvt_bin(
    const float2* __restrict__ x2, unsigned* __restrict__ xh,
    const int* __restrict__ eidx, const float4* __restrict__ elab4,
    int* __restrict__ cnt_r, int* __restrict__ cnt_c,
    uint2* __restrict__ ent_r, uint2* __restrict__ ent_c,
    const float* __restrict__ w, const float* __restrict__ tw,
    u16* __restrict__ wb, int n2, int E, int nbk, int nchunk)
{
    __shared__ int smem[2048];   // 8KB union: bin cB[1024] / wb P[8][256]
    const int t = threadIdx.x;
    const unsigned bid = blockIdx.x;

    if (bid < 2u * nchunk) {
        // ---------------- bin role ----------------
        int* cB = smem;
        const int dir = (bid >= (unsigned)nchunk);
        const int base = (dir ? bid - nchunk : bid) * CHUNK;
        const int* __restrict__ osrc = eidx + (dir ? (size_t)E : 0);   // own id
        const int* __restrict__ psrc = eidx + (dir ? 0 : (size_t)E);   // partner id
        int* __restrict__ cnt = dir ? cnt_c : cnt_r;
        uint2* __restrict__ ent = dir ? ent_c : ent_r;

        for (int i = t; i < nbk; i += 256) cB[i] = 0;
        __syncthreads();

        int4 own4[4], par4[4];
        unsigned lq[16];
        bool ok[4];
        #pragma unroll
        for (int jj = 0; jj < 4; ++jj) {
            const int e0 = base + (jj * 256 + t) * 4;
            ok[jj] = (e0 < E);             // E % 4 == 0; chunk-aligned
            if (ok[jj]) {
                own4[jj] = *(const int4*)(osrc + e0);
                par4[jj] = *(const int4*)(psrc + e0);
                #pragma unroll
                for (int k = 0; k < 4; ++k) {
                    const float4 lb = elab4[e0 + k];
                    const unsigned q0 = (unsigned)(lb.x * 255.f + 0.5f);
                    const unsigned q1 = (unsigned)(lb.y * 255.f + 0.5f);
                    const unsigned q2 = (unsigned)(lb.z * 255.f + 0.5f);
                    const unsigned q3 = (unsigned)(lb.w * 255.f + 0.5f);
                    lq[jj * 4 + k] = q0 | (q1 << 8) | (q2 << 16) | (q3 << 24);
                }
                atomicAdd(&cB[((unsigned)own4[jj].x) >> 7], 1);
                atomicAdd(&cB[((unsigned)own4[jj].y) >> 7], 1);
                atomicAdd(&cB[((unsigned)own4[jj].z) >> 7], 1);
                atomicAdd(&cB[((unsigned)own4[jj].w) >> 7], 1);
            }
        }
        __syncthreads();
        for (int b = t; b < nbk; b += 256) {
            const int c = cB[b];
            cB[b] = c ? ((b << 12) + atomicAdd(&cnt[b], c)) : 0;   // CAPSEG==4096
        }
        __syncthreads();
        #pragma unroll
        for (int jj = 0; jj < 4; ++jj) {
            if (ok[jj]) {
                const int owns[4] = {own4[jj].x, own4[jj].y, own4[jj].z, own4[jj].w};
                const int pars[4] = {par4[jj].x, par4[jj].y, par4[jj].z, par4[jj].w};
                #pragma unroll
                for (int k = 0; k < 4; ++k) {
                    const unsigned own = (unsigned)owns[k];
                    const int p = atomicAdd(&cB[own >> 7], 1);
                    ent[p] = make_uint2((unsigned)pars[k] | ((own & 127u) << 17),
                                        lq[jj * 4 + k]);
                }
            }
        }
        return;
    }

    if (bid < 2u * nchunk + NB_CVT) {
        // ---------------- cvt role ----------------
        const int cb = bid - 2 * nchunk;
        const int gsz = NB_CVT * 256;
        for (int i = cb * 256 + t; i < n2; i += gsz) {
            const float2 v = x2[i];
            xh[i] = pk_bf16(v.x, v.y);
        }
        return;
    }

    // ---------------- wb-pack role ----------------
    // wb[((ks*16+ct)*64+lane)*8+j] = B_eff[ks*32+(lane>>4)*8+j][ct*16+(lane&15)]
    // B_eff rows: [0:128)=W[0:128], [128:256)=W[256:384], [256:260)=P1,
    // [260:264)=P3, zero pad to 288.
    float (*P)[256] = (float(*)[256])smem;
    const int pid0 = (bid - 2 * nchunk - NB_CVT) * 256;
    if (pid0 + 255 >= 8192) {              // packs some k>=256 -> needs P1/P3
        for (int q = t; q < 2048; q += 256) {
            const int l = q >> 8;
            const int cidx = q & 255;
            const int lr = l & 3;
            const int off = (l < 4) ? 128 : 384;
            float s = 0.f;
            for (int c = 0; c < 128; ++c)
                s = fmaf(tw[lr * 128 + c], w[(size_t)(off + c) * 256 + cidx], s);
            P[l][cidx] = s;
        }
        __syncthreads();
    }
    const int pid = pid0 + t;
    if (pid >= 9 * 16 * 64) return;
    const int ks = pid >> 10;
    const int ct = (pid >> 6) & 15;
    const int l  = pid & 63;
    const int col = ct * 16 + (l & 15);
    const int k0 = ks * 32 + ((l >> 4) << 3);
    u16 v[8];
    #pragma unroll
    for (int j = 0; j < 8; ++j) {
        const int k = k0 + j;
        float f = 0.f;
        if (k < 128)      f = w[(size_t)k * 256 + col];
        else if (k < 256) f = w[(size_t)(k + 128) * 256 + col];
        else if (k < 264) f = P[k - 256][col];
        v[j] = f2bf(f);
    }
    *(uint4*)(wb + (size_t)pid * 8) = *(uint4*)v;
}

__device__ inline void addrow(float* acc, const uint4 r) {
    const float2 a = upk_bf16(r.x), b = upk_bf16(r.y),
                 c = upk_bf16(r.z), d = upk_bf16(r.w);
    acc[0] += a.x; acc[1] += a.y; acc[2] += b.x; acc[3] += b.y;
    acc[4] += c.x; acc[5] += c.y; acc[6] += d.x; acc[7] += d.y;
}

// Fused CSR sort (in LDS) + accumulate: block per (bucket, direction).
__global__ __launch_bounds__(256) void sort_accum(
    const uint2* __restrict__ ent1_r, const uint2* __restrict__ ent1_c,
    const int* __restrict__ cnt_r, const int* __restrict__ cnt_c,
    const uint4* __restrict__ xh4,
    uint4* __restrict__ om4, uint4* __restrict__ im4,
    u16* __restrict__ lab_h, int nn, int nbk)
{
    __shared__ unsigned sorted[CAPSEG];
    __shared__ int hist[BK], sc[BK], curs[BK];
    __shared__ u64 labacc[BK];
    const int t = threadIdx.x;
    const int dir = (blockIdx.x >= (unsigned)nbk);
    const int b = blockIdx.x - (dir ? nbk : 0);
    const uint2* __restrict__ buf1 = (dir ? ent1_c : ent1_r) + ((size_t)b * CAPSEG);
    uint4* __restrict__ mean4 = dir ? im4 : om4;
    int cnt = (dir ? cnt_c : cnt_r)[b];
    if (cnt > CAPSEG) cnt = CAPSEG;        // statistically impossible; safety clamp

    if (t < BK) { hist[t] = 0; labacc[t] = 0ull; }
    __syncthreads();
    for (int i = t; i < cnt; i += 256) {
        const uint2 en = buf1[i];
        const unsigned local = en.x >> 17;
        atomicAdd(&hist[local], 1);
        const unsigned lv = en.y;
        const u64 spread = (u64)(lv & 255u) | ((u64)((lv >> 8) & 255u) << 16)
                         | ((u64)((lv >> 16) & 255u) << 32) | ((u64)(lv >> 24) << 48);
        atomicAdd(&labacc[local], spread);
    }
    __syncthreads();
    if (t < BK) sc[t] = hist[t];
    __syncthreads();
    for (int s = 1; s < BK; s <<= 1) {
        int v = 0;
        if (t < BK && t >= s) v = sc[t - s];
        __syncthreads();
        if (t < BK) sc[t] += v;
        __syncthreads();
    }
    if (t < BK) {
        curs[t] = sc[t] - hist[t];
        const int gn = b * BK + t;
        if (gn < nn) {
            const u64 sv = labacc[t];
            const float inv = (1.f / 255.f) / fmaxf((float)hist[t], 1.f);
            u16 lm[4];
            #pragma unroll
            for (int l = 0; l < 4; ++l)
                lm[l] = f2bf((float)((sv >> (16 * l)) & 0xFFFFu) * inv);
            *(uint2*)(lab_h + (size_t)gn * 8 + dir * 4) = *(uint2*)lm;
        }
    }
    __syncthreads();
    for (int i = t; i < cnt; i += 256) {
        const uint2 en = buf1[i];
        const int p = atomicAdd(&curs[en.x >> 17], 1);
        sorted[p] = en.x & 0x1FFFFu;       // partner only
    }
    __syncthreads();

    // accumulate: wave per node; uniform 4-deep gather pipeline (16 entries/iter)
    const int wid = t >> 6;
    const int lane = t & 63;
    const int g = lane >> 4;               // edge group 0..3
    const int sl = lane & 15;              // 16B sub-row
    for (int local = wid; local < BK; local += 4) {
        const int gn = b * BK + local;
        if (gn >= nn) continue;            // wave-uniform branch
        const int segC = hist[local];
        const int segS = sc[local] - segC;
        float acc[8] = {0.f, 0.f, 0.f, 0.f, 0.f, 0.f, 0.f, 0.f};
        for (int i = 0; i < segC; i += 16) {
            const int rem = segC - i;
            const bool h0 = (g < rem);
            const bool h1 = (g + 4 < rem);
            const bool h2 = (g + 8 < rem);
            const bool h3 = (g + 12 < rem);
            const unsigned p0 = h0 ? sorted[segS + i + g] : 0u;
            const unsigned p1 = h1 ? sorted[segS + i + 4 + g] : 0u;
            const unsigned p2 = h2 ? sorted[segS + i + 8 + g] : 0u;
            const unsigned p3 = h3 ? sorted[segS + i + 12 + g] : 0u;
            uint4 r0, r1, r2, r3;
            if (h0) r0 = xh4[(size_t)p0 * 16 + sl];
            if (h1) r1 = xh4[(size_t)p1 * 16 + sl];
            if (h2) r2 = xh4[(size_t)p2 * 16 + sl];
            if (h3) r3 = xh4[(size_t)p3 * 16 + sl];
            if (h0) addrow(acc, r0);
            if (h1) addrow(acc, r1);
            if (h2) addrow(acc, r2);
            if (h3) addrow(acc, r3);
        }
        #pragma unroll
        for (int j = 0; j < 8; ++j) {
            acc[j] += __shfl_xor(acc[j], 16);
            acc[j] += __shfl_xor(acc[j], 32);
        }
        if (g == 0) {
            const float inv = 1.0f / fmaxf((float)segC, 1.0f);
            uint4 o;
            o.x = pk_bf16(acc[0] * inv, acc[1] * inv);
            o.y = pk_bf16(acc[2] * inv, acc[3] * inv);
            o.z = pk_bf16(acc[4] * inv, acc[5] * inv);
            o.w = pk_bf16(acc[6] * inv, acc[7] * inv);
            mean4[(size_t)gn * 16 + sl] = o;
        }
    }
}

// MFMA GEMM, A direct from global (no LDS, no barrier).
// out[64 x 256] per block; K=288 (om 128 | im 128 | labels 8 | pad 24).
__global__ __launch_bounds__(256) void gemm_mfma(
    const u16* __restrict__ om_h, const u16* __restrict__ im_h,
    const u16* __restrict__ lab_h, const u16* __restrict__ wb,
    const float* __restrict__ bias, float* __restrict__ out, int nn)
{
    const int t = threadIdx.x;
    const int w = t >> 6;
    const int lane = t & 63;
    const int m15 = lane & 15;
    const int kq  = lane >> 4;
    const int node0 = blockIdx.x * 64;

    f32x4 acc[4][4];
    #pragma unroll
    for (int i = 0; i < 4; ++i)
        #pragma unroll
        for (int j = 0; j < 4; ++j)
            acc[i][j] = (f32x4){0.f, 0.f, 0.f, 0.f};

    for (int ks = 0; ks < 9; ++ks) {
        const int k0 = ks * 32 + kq * 8;
        bf16x8 af[4], bfr[4];
        #pragma unroll
        for (int nt = 0; nt < 4; ++nt) {
            const int gn = node0 + nt * 16 + m15;
            bf16x8 a = (bf16x8){0, 0, 0, 0, 0, 0, 0, 0};
            if (gn < nn && k0 < 264) {
                const u16* p = (k0 < 128) ? om_h + (size_t)gn * 128 + k0
                             : (k0 < 256) ? im_h + (size_t)gn * 128 + (k0 - 128)
                                          : lab_h + (size_t)gn * 8;
                a = *(const bf16x8*)p;
            }
            af[nt] = a;
        }
        #pragma unroll
        for (int c2 = 0; c2 < 4; ++c2)
            bfr[c2] = *(const bf16x8*)(wb + ((size_t)((ks * 16 + w * 4 + c2) * 64 + lane)) * 8);
        #pragma unroll
        for (int nt = 0; nt < 4; ++nt)
            #pragma unroll
            for (int c2 = 0; c2 < 4; ++c2)
                acc[nt][c2] = __builtin_amdgcn_mfma_f32_16x16x32_bf16(
                    af[nt], bfr[c2], acc[nt][c2], 0, 0, 0);
    }

    #pragma unroll
    for (int nt = 0; nt < 4; ++nt) {
        const int gnb = node0 + nt * 16 + kq * 4;
        #pragma unroll
        for (int c2 = 0; c2 < 4; ++c2) {
            const int oc = w * 64 + c2 * 16 + m15;
            const float bv = bias[oc];
            #pragma unroll
            for (int r = 0; r < 4; ++r) {
                const int gn = gnb + r;
                if (gn < nn)
                    __builtin_nontemporal_store(acc[nt][c2][r] + bv,
                                                &out[(size_t)gn * 256 + oc]);
            }
        }
    }
}

extern "C" void kernel_launch(void* const* d_in, const int* in_sizes, int n_in,
                              void* d_out, int out_size, void* d_ws, size_t ws_size,
                              hipStream_t stream) {
    const float* x      = (const float*)d_in[0];
    const int*   eidx   = (const int*)d_in[1];
    const float* elabel = (const float*)d_in[2];
    const float* weight = (const float*)d_in[3];
    const float* tw     = (const float*)d_in[4];
    const float* bias   = (const float*)d_in[5];

    const int n = in_sizes[0] / 128;       // n_nodes (100000 < 2^17)
    const int E = in_sizes[2] / 4;         // n_edges (1.6M, multiple of 4)
    const int nbk = (n + BK - 1) / BK;     // buckets (782 <= 1024)
    const int nchunk = (E + CHUNK - 1) / CHUNK;

    // ---- workspace layout (bytes; 16B alignment for uint4 rows) ----
    char* wsb = (char*)d_ws;
    u16* om_h    = (u16*)wsb;   wsb += (size_t)n * 256;
    u16* im_h    = (u16*)wsb;   wsb += (size_t)n * 256;
    u16* lab_h   = (u16*)wsb;   wsb += (size_t)n * 16;   // per node: labr[4] ++ labc[4]
    u16* wb      = (u16*)wsb;   wsb += 9216 * 16;
    int* cnt_r   = (int*)wsb;   wsb += nbk * 4;          // memset region (2*nbk ints)
    int* cnt_c   = (int*)wsb;   wsb += nbk * 4;

    // ---- d_out staging (76.8 MB of 102.4), consumed before gemm ----
    unsigned* xh = (unsigned*)d_out;                       // n*64 u32 = 25.6 MB
    uint2* ent1_r = (uint2*)(xh + (size_t)n * 64);         // nbk*CAPSEG*8 = 25.6 MB
    uint2* ent1_c = ent1_r + (size_t)nbk * CAPSEG;         // 25.6 MB

    hipMemsetAsync(cnt_r, 0, (size_t)2 * nbk * sizeof(int), stream);

    hipLaunchKernelGGL(cvt_bin, dim3(2 * nchunk + NB_CVT + 36), dim3(256), 0, stream,
                       (const float2*)x, xh, eidx, (const float4*)elabel,
                       cnt_r, cnt_c, ent1_r, ent1_c,
                       weight, tw, wb, n * 64, E, nbk, nchunk);

    hipLaunchKernelGGL(sort_accum, dim3(2 * nbk), dim3(256), 0, stream,
                       ent1_r, ent1_c, cnt_r, cnt_c, (const uint4*)xh,
                       (uint4*)om_h, (uint4*)im_h, lab_h, n, nbk);

    hipLaunchKernelGGL(gemm_mfma, dim3((n + 63) / 64), dim3(256), 0, stream,
                       om_h, im_h, lab_h, wb, bias, (float*)d_out, n);
}